// Round 1
// baseline (126.115 us; speedup 1.0000x reference)
//
#include <hip/hip_runtime.h>
#include <hip/hip_bf16.h>
#include <math.h>

#define S_LEN   4096
#define HID     2048
#define NB      8
#define SC      64            // s-chunks for partial pooling
#define S_PER   (S_LEN / SC)  // 64 rows per chunk
#define R       16            // TOTAL_RANK
#define AD      32            // ADAPT_DIM

// ---------------- Kernel 1: partial mean-pool over S ----------------
// grid (2 hc, 64 sc, 8 b), block 256. Each thread sums 64 s-rows of 4
// consecutive h (float4). Writes partial[b][sc][h].
__global__ void pool_partial(const float* __restrict__ hs,
                             float* __restrict__ partial) {
    int t  = threadIdx.x;         // 0..255
    int hc = blockIdx.x;          // 0..1
    int sc = blockIdx.y;          // 0..63
    int b  = blockIdx.z;          // 0..7
    int h  = hc * 1024 + t * 4;
    const float* base = hs + ((size_t)b * S_LEN + (size_t)sc * S_PER) * HID + h;
    float4 acc = make_float4(0.f, 0.f, 0.f, 0.f);
#pragma unroll 8
    for (int s = 0; s < S_PER; ++s) {
        float4 v = *(const float4*)(base + (size_t)s * HID);
        acc.x += v.x; acc.y += v.y; acc.z += v.z; acc.w += v.w;
    }
    *(float4*)(partial + ((size_t)b * SC + sc) * HID + h) = acc;
}

// ---------------- Kernel 2: reduce partials -> pooled mean ----------------
// grid 64, block 256: one thread per (b,h).
__global__ void reduce_pool(const float* __restrict__ partial,
                            float* __restrict__ pooled) {
    int n = blockIdx.x * 256 + threadIdx.x;   // 0..16383
    int b = n >> 11;                          // /2048
    int h = n & 2047;
    const float* p = partial + ((size_t)b * SC) * HID + h;
    float s = 0.f;
#pragma unroll 8
    for (int sc = 0; sc < SC; ++sc) s += p[(size_t)sc * HID];
    pooled[n] = s * (1.0f / (float)S_LEN);
}

// ---------------- Kernel 3: controller MLP + top-k mask ----------------
// grid 8 (one block per batch), block 256.
__global__ void controller(const float* __restrict__ pooled,
                           const float* __restrict__ W1,
                           const float* __restrict__ b1,
                           const float* __restrict__ gamma,
                           const float* __restrict__ beta,
                           const float* __restrict__ W2,
                           const float* __restrict__ b2v,
                           const float* __restrict__ mlog,
                           const float* __restrict__ rsc,
                           float* __restrict__ maskscale) {
    __shared__ float xpart[8][AD];
    __shared__ float xg[AD];
    __shared__ float comb[R];
    int b = blockIdx.x, t = threadIdx.x;
    int j = t & 31, g = t >> 5;               // 8 groups of 32

    // x[j] = pooled[b] . W1[:,j]  (each group strides h by 8)
    const float* pb = pooled + (size_t)b * HID;
    float ps = 0.f;
    for (int h = g; h < HID; h += 8) ps += pb[h] * W1[(size_t)h * AD + j];
    xpart[g][j] = ps;
    __syncthreads();

    if (t < AD) {
        float x = b1[t];
#pragma unroll
        for (int gg = 0; gg < 8; ++gg) x += xpart[gg][t];
        xpart[0][t] = x;
    }
    __syncthreads();

    if (t < AD) {
        float mu = 0.f;
#pragma unroll
        for (int k = 0; k < AD; ++k) mu += xpart[0][k];
        mu *= (1.0f / AD);
        float var = 0.f;
#pragma unroll
        for (int k = 0; k < AD; ++k) { float d = xpart[0][k] - mu; var += d * d; }
        var *= (1.0f / AD);
        float x = (xpart[0][t] - mu) * rsqrtf(var + 1e-5f) * gamma[t] + beta[t];
        // exact GELU: 0.5*x*(1+erf(x/sqrt(2)))
        xg[t] = 0.5f * x * (1.0f + erff(x * 0.70710678118654752f));
    }
    __syncthreads();

    if (t < R) {
        float lg = b2v[t];
#pragma unroll
        for (int k = 0; k < AD; ++k) lg += xg[k] * W2[(size_t)k * R + t];
        comb[t] = lg + mlog[t];
    }
    __syncthreads();

    if (t < R) {
        float v = comb[t];
        int cnt = 0;
#pragma unroll
        for (int k = 0; k < R; ++k)
            cnt += (comb[k] > v) || (comb[k] == v && k < t);
        maskscale[b * R + t] = (cnt < 8) ? rsc[t] : 0.f;
    }
}

// ---------------- Kernel 4: masked scale + 16-pt Hadamard ----------------
// rows = 8*4096 = 32768. grid 128, block 256 -> one row per thread.
// Each block lies entirely within one batch (16 blocks per batch).
__global__ void apply_hadamard(const float* __restrict__ ra,
                               const float* __restrict__ maskscale,
                               float* __restrict__ out) {
    __shared__ float ms[R];
    int t = threadIdx.x;
    int blk = blockIdx.x;
    int b = blk >> 4;                 // 16 blocks per batch
    if (t < R) ms[t] = maskscale[b * R + t];
    __syncthreads();

    size_t row = (size_t)blk * 256 + t;
    const float* src = ra + row * R;
    float a[R];
#pragma unroll
    for (int i = 0; i < 4; ++i) {
        float4 v = ((const float4*)src)[i];
        a[4 * i + 0] = v.x; a[4 * i + 1] = v.y;
        a[4 * i + 2] = v.z; a[4 * i + 3] = v.w;
    }
#pragma unroll
    for (int r = 0; r < R; ++r) a[r] *= ms[r];

    // FWHT-16 (Sylvester ordering), then scale by 1/32
    // (recursive /sqrt(n) at every level => total 1/32)
#pragma unroll
    for (int hstep = 1; hstep < R; hstep <<= 1) {
#pragma unroll
        for (int i = 0; i < R; ++i) {
            if ((i & hstep) == 0) {
                float u = a[i], v = a[i | hstep];
                a[i] = u + v; a[i | hstep] = u - v;
            }
        }
    }

    float* dst = out + row * R;
#pragma unroll
    for (int i = 0; i < 4; ++i) {
        float4 v;
        v.x = a[4 * i + 0] * 0.03125f; v.y = a[4 * i + 1] * 0.03125f;
        v.z = a[4 * i + 2] * 0.03125f; v.w = a[4 * i + 3] * 0.03125f;
        ((float4*)dst)[i] = v;
    }
}

extern "C" void kernel_launch(void* const* d_in, const int* in_sizes, int n_in,
                              void* d_out, int out_size, void* d_ws, size_t ws_size,
                              hipStream_t stream) {
    const float* hs    = (const float*)d_in[0];  // (8,4096,2048)
    const float* ra    = (const float*)d_in[1];  // (8,4096,16)
    const float* W1    = (const float*)d_in[2];  // (2048,32)
    const float* b1    = (const float*)d_in[3];  // (32)
    const float* gamma = (const float*)d_in[4];  // (32)
    const float* beta  = (const float*)d_in[5];  // (32)
    const float* W2    = (const float*)d_in[6];  // (32,16)
    const float* b2v   = (const float*)d_in[7];  // (16)
    const float* mlog  = (const float*)d_in[8];  // (16)
    const float* rsc   = (const float*)d_in[9];  // (16)
    float* out = (float*)d_out;

    float* partial   = (float*)d_ws;                      // 8*64*2048 f32 = 4 MB
    float* pooled    = partial + (size_t)NB * SC * HID;   // 8*2048 f32 = 64 KB
    float* maskscale = pooled + (size_t)NB * HID;         // 128 f32

    pool_partial  <<<dim3(2, SC, NB), 256, 0, stream>>>(hs, partial);
    reduce_pool   <<<64, 256, 0, stream>>>(partial, pooled);
    controller    <<<NB, 256, 0, stream>>>(pooled, W1, b1, gamma, beta,
                                           W2, b2v, mlog, rsc, maskscale);
    apply_hadamard<<<128, 256, 0, stream>>>(ra, maskscale, out);
}

// Round 2
// 65.300 us; speedup vs baseline: 1.9313x; 1.9313x over previous
//
#include <hip/hip_runtime.h>
#include <hip/hip_bf16.h>
#include <math.h>

#define S_LEN   4096
#define HID     2048
#define NB      8
#define SC      64            // s-chunks: one block per 64 rows
#define S_PER   (S_LEN / SC)  // 64 rows per block
#define R       16            // TOTAL_RANK
#define AD      32            // ADAPT_DIM

// ---------------- Kernel 1: fused mean-pool + W1 projection ----------------
// grid (64 sc, 8 b), block 256. Each block streams 64 full rows (512 KB),
// reduces them to a 2048-float h-sum in LDS, projects onto W1 (L2-resident),
// and writes a 32-float partial x contribution. No pooled/partial buffer.
__global__ void pool_proj(const float* __restrict__ hs,
                          const float* __restrict__ W1,
                          float* __restrict__ xpart) {
    __shared__ float hsum[HID];        // 8 KB
    __shared__ float cpart[8][AD];     // 1 KB
    int t  = threadIdx.x;              // 0..255
    int sc = blockIdx.x;               // 0..63
    int b  = blockIdx.y;               // 0..7

    const float* base = hs + ((size_t)b * S_LEN + (size_t)sc * S_PER) * HID;
    const float* p0 = base + t * 4;           // columns [t*4, t*4+3]
    const float* p1 = base + 1024 + t * 4;    // columns [1024+t*4, ...]
    float4 a0 = make_float4(0.f, 0.f, 0.f, 0.f);
    float4 a1 = make_float4(0.f, 0.f, 0.f, 0.f);
#pragma unroll 8
    for (int s = 0; s < S_PER; ++s) {
        float4 v0 = *(const float4*)(p0 + (size_t)s * HID);
        float4 v1 = *(const float4*)(p1 + (size_t)s * HID);
        a0.x += v0.x; a0.y += v0.y; a0.z += v0.z; a0.w += v0.w;
        a1.x += v1.x; a1.y += v1.y; a1.z += v1.z; a1.w += v1.w;
    }
    *(float4*)&hsum[t * 4]        = a0;
    *(float4*)&hsum[1024 + t * 4] = a1;
    __syncthreads();

    // project: c[j] = sum_h hsum[h] * W1[h][j]; 8 groups of 32 lanes,
    // group g owns h in [g*256, g*256+256)
    int j = t & 31, g = t >> 5;
    const float* w = W1 + (size_t)(g * 256) * AD + j;
    float c = 0.f;
#pragma unroll 4
    for (int k = 0; k < 256; ++k)
        c += hsum[g * 256 + k] * w[(size_t)k * AD];
    cpart[g][j] = c;
    __syncthreads();

    if (t < AD) {
        float s = 0.f;
#pragma unroll
        for (int gg = 0; gg < 8; ++gg) s += cpart[gg][t];
        xpart[((size_t)(b * SC + sc)) * AD + t] = s;
    }
}

// ---------------- Kernel 2: reduce xpart + LN + GELU + W2 + topk ----------
// grid 8 (one block per batch), block 256.
__global__ void controller2(const float* __restrict__ xpart,
                            const float* __restrict__ b1,
                            const float* __restrict__ gamma,
                            const float* __restrict__ beta,
                            const float* __restrict__ W2,
                            const float* __restrict__ b2v,
                            const float* __restrict__ mlog,
                            const float* __restrict__ rsc,
                            float* __restrict__ maskscale) {
    __shared__ float xp[8][AD];
    __shared__ float xv[AD];
    __shared__ float xg[AD];
    __shared__ float comb[R];
    int b = blockIdx.x, t = threadIdx.x;
    int j = t & 31, g = t >> 5;

    // reduce 64 partial rows for this batch: group g sums rows g*8..g*8+7
    const float* xb = xpart + (size_t)b * SC * AD;
    float s = 0.f;
#pragma unroll
    for (int r = 0; r < 8; ++r) s += xb[(size_t)(g * 8 + r) * AD + j];
    xp[g][j] = s;
    __syncthreads();

    if (t < AD) {
        float x = 0.f;
#pragma unroll
        for (int gg = 0; gg < 8; ++gg) x += xp[gg][t];
        xv[t] = x * (1.0f / (float)S_LEN) + b1[t];
    }
    __syncthreads();

    if (t < AD) {
        float mu = 0.f;
#pragma unroll
        for (int k = 0; k < AD; ++k) mu += xv[k];
        mu *= (1.0f / AD);
        float var = 0.f;
#pragma unroll
        for (int k = 0; k < AD; ++k) { float d = xv[k] - mu; var += d * d; }
        var *= (1.0f / AD);
        float x = (xv[t] - mu) * rsqrtf(var + 1e-5f) * gamma[t] + beta[t];
        xg[t] = 0.5f * x * (1.0f + erff(x * 0.70710678118654752f));  // exact GELU
    }
    __syncthreads();

    if (t < R) {
        float lg = b2v[t];
#pragma unroll
        for (int k = 0; k < AD; ++k) lg += xg[k] * W2[(size_t)k * R + t];
        comb[t] = lg + mlog[t];
    }
    __syncthreads();

    if (t < R) {
        float v = comb[t];
        int cnt = 0;
#pragma unroll
        for (int k = 0; k < R; ++k)
            cnt += (comb[k] > v) || (comb[k] == v && k < t);
        maskscale[b * R + t] = (cnt < 8) ? rsc[t] : 0.f;
    }
}

// ---------------- Kernel 3: masked scale + 16-pt Hadamard ----------------
// rows = 8*4096 = 32768. grid 128, block 256 -> one row per thread.
__global__ void apply_hadamard(const float* __restrict__ ra,
                               const float* __restrict__ maskscale,
                               float* __restrict__ out) {
    __shared__ float ms[R];
    int t = threadIdx.x;
    int blk = blockIdx.x;
    int b = blk >> 4;                 // 16 blocks per batch
    if (t < R) ms[t] = maskscale[b * R + t];
    __syncthreads();

    size_t row = (size_t)blk * 256 + t;
    const float* src = ra + row * R;
    float a[R];
#pragma unroll
    for (int i = 0; i < 4; ++i) {
        float4 v = ((const float4*)src)[i];
        a[4 * i + 0] = v.x; a[4 * i + 1] = v.y;
        a[4 * i + 2] = v.z; a[4 * i + 3] = v.w;
    }
#pragma unroll
    for (int r = 0; r < R; ++r) a[r] *= ms[r];

    // FWHT-16 (Sylvester ordering); recursive /sqrt(n) => total 1/32
#pragma unroll
    for (int hstep = 1; hstep < R; hstep <<= 1) {
#pragma unroll
        for (int i = 0; i < R; ++i) {
            if ((i & hstep) == 0) {
                float u = a[i], v = a[i | hstep];
                a[i] = u + v; a[i | hstep] = u - v;
            }
        }
    }

    float* dst = out + row * R;
#pragma unroll
    for (int i = 0; i < 4; ++i) {
        float4 v;
        v.x = a[4 * i + 0] * 0.03125f; v.y = a[4 * i + 1] * 0.03125f;
        v.z = a[4 * i + 2] * 0.03125f; v.w = a[4 * i + 3] * 0.03125f;
        ((float4*)dst)[i] = v;
    }
}

extern "C" void kernel_launch(void* const* d_in, const int* in_sizes, int n_in,
                              void* d_out, int out_size, void* d_ws, size_t ws_size,
                              hipStream_t stream) {
    const float* hs    = (const float*)d_in[0];  // (8,4096,2048)
    const float* ra    = (const float*)d_in[1];  // (8,4096,16)
    const float* W1    = (const float*)d_in[2];  // (2048,32)
    const float* b1    = (const float*)d_in[3];  // (32)
    const float* gamma = (const float*)d_in[4];  // (32)
    const float* beta  = (const float*)d_in[5];  // (32)
    const float* W2    = (const float*)d_in[6];  // (32,16)
    const float* b2v   = (const float*)d_in[7];  // (16)
    const float* mlog  = (const float*)d_in[8];  // (16)
    const float* rsc   = (const float*)d_in[9];  // (16)
    float* out = (float*)d_out;

    float* xpart     = (float*)d_ws;                       // 512*32 f32 = 64 KB
    float* maskscale = xpart + (size_t)NB * SC * AD;       // 128 f32

    pool_proj     <<<dim3(SC, NB), 256, 0, stream>>>(hs, W1, xpart);
    controller2   <<<NB, 256, 0, stream>>>(xpart, b1, gamma, beta,
                                           W2, b2v, mlog, rsc, maskscale);
    apply_hadamard<<<128, 256, 0, stream>>>(ra, maskscale, out);
}

// Round 3
// 56.848 us; speedup vs baseline: 2.2185x; 1.1487x over previous
//
#include <hip/hip_runtime.h>
#include <hip/hip_bf16.h>
#include <math.h>

#define S_LEN   4096
#define HID     2048
#define NB      8
#define SC      128           // s-chunks: one block per 32 rows
#define S_PER   (S_LEN / SC)  // 32 rows per block
#define R       16            // TOTAL_RANK
#define AD      32            // ADAPT_DIM

typedef float f4 __attribute__((ext_vector_type(4)));

// ---------------- Kernel 1: fused mean-pool + W1 projection ----------------
// grid (128 sc, 8 b), block 256 -> 1024 blocks (4/CU, full wave occupancy).
// Each block streams 32 full rows (256 KB), reduces to a 2048-float h-sum in
// LDS, projects onto W1 (L2-resident), writes a 32-float partial x row.
__global__ void pool_proj(const float* __restrict__ hs,
                          const float* __restrict__ W1,
                          float* __restrict__ xpart) {
    __shared__ float hsum[HID];        // 8 KB
    __shared__ float cpart[8][AD];     // 1 KB
    int t  = threadIdx.x;              // 0..255
    int sc = blockIdx.x;               // 0..127
    int b  = blockIdx.y;               // 0..7

    const float* base = hs + ((size_t)b * S_LEN + (size_t)sc * S_PER) * HID;
    const f4* p0 = (const f4*)(base + t * 4);          // cols [t*4 .. t*4+3]
    const f4* p1 = (const f4*)(base + 1024 + t * 4);   // cols [1024+t*4 ..]
    f4 a0 = (f4)(0.f);
    f4 a1 = (f4)(0.f);
#pragma unroll 8
    for (int s = 0; s < S_PER; ++s) {
        f4 v0 = __builtin_nontemporal_load(p0 + (size_t)s * (HID / 4));
        f4 v1 = __builtin_nontemporal_load(p1 + (size_t)s * (HID / 4));
        a0 += v0;
        a1 += v1;
    }
    *(f4*)&hsum[t * 4]        = a0;
    *(f4*)&hsum[1024 + t * 4] = a1;
    __syncthreads();

    // project: c[j] = sum_h hsum[h] * W1[h][j]; 8 groups of 32 lanes,
    // group g owns h in [g*256, g*256+256)
    int j = t & 31, g = t >> 5;
    const float* w = W1 + (size_t)(g * 256) * AD + j;
    float c = 0.f;
#pragma unroll 4
    for (int k = 0; k < 256; ++k)
        c += hsum[g * 256 + k] * w[(size_t)k * AD];
    cpart[g][j] = c;
    __syncthreads();

    if (t < AD) {
        float s = 0.f;
#pragma unroll
        for (int gg = 0; gg < 8; ++gg) s += cpart[gg][t];
        xpart[((size_t)(b * SC + sc)) * AD + t] = s;
    }
}

// ---- Kernel 2: per-block controller redo + masked scale + Hadamard ----
// grid 256, block 128 -> one row per thread, 128 rows per block, 32 blocks
// per batch. Every block redundantly recomputes the tiny controller for its
// batch from xpart (16 KB, L2-hot) -> deterministic identical mask; then
// streams its 128 rows of rank_activations through the masked FWHT-16.
__global__ void ctrl_hadamard(const float* __restrict__ xpart,
                              const float* __restrict__ b1,
                              const float* __restrict__ gamma,
                              const float* __restrict__ beta,
                              const float* __restrict__ W2,
                              const float* __restrict__ b2v,
                              const float* __restrict__ mlog,
                              const float* __restrict__ rsc,
                              const float* __restrict__ ra,
                              float* __restrict__ out) {
    __shared__ float xp[4][AD];
    __shared__ float xv[AD];
    __shared__ float xg[AD];
    __shared__ float comb[R];
    __shared__ float ms[R];
    int t   = threadIdx.x;            // 0..127
    int blk = blockIdx.x;             // 0..255
    int b   = blk >> 5;               // 32 blocks per batch

    // --- controller (redundant per block, identical across a batch) ---
    int j = t & 31, g = t >> 5;       // 4 groups of 32
    const float* xb = xpart + (size_t)b * SC * AD;
    float s = 0.f;
#pragma unroll 8
    for (int r = 0; r < 32; ++r) s += xb[(size_t)(g * 32 + r) * AD + j];
    xp[g][j] = s;
    __syncthreads();

    if (t < AD) {
        float x = 0.f;
#pragma unroll
        for (int gg = 0; gg < 4; ++gg) x += xp[gg][t];
        xv[t] = x * (1.0f / (float)S_LEN) + b1[t];
    }
    __syncthreads();

    if (t < AD) {
        float mu = 0.f;
#pragma unroll
        for (int k = 0; k < AD; ++k) mu += xv[k];
        mu *= (1.0f / AD);
        float var = 0.f;
#pragma unroll
        for (int k = 0; k < AD; ++k) { float d = xv[k] - mu; var += d * d; }
        var *= (1.0f / AD);
        float x = (xv[t] - mu) * rsqrtf(var + 1e-5f) * gamma[t] + beta[t];
        xg[t] = 0.5f * x * (1.0f + erff(x * 0.70710678118654752f));  // exact GELU
    }
    __syncthreads();

    if (t < R) {
        float lg = b2v[t];
#pragma unroll
        for (int k = 0; k < AD; ++k) lg += xg[k] * W2[(size_t)k * R + t];
        comb[t] = lg + mlog[t];
    }
    __syncthreads();

    if (t < R) {
        float v = comb[t];
        int cnt = 0;
#pragma unroll
        for (int k = 0; k < R; ++k)
            cnt += (comb[k] > v) || (comb[k] == v && k < t);
        ms[t] = (cnt < 8) ? rsc[t] : 0.f;
    }
    __syncthreads();

    // --- masked scale + FWHT-16 (one row per thread) ---
    size_t row = (size_t)blk * 128 + t;
    const f4* src = (const f4*)(ra + row * R);
    float a[R];
#pragma unroll
    for (int i = 0; i < 4; ++i) {
        f4 v = __builtin_nontemporal_load(src + i);
        a[4 * i + 0] = v.x; a[4 * i + 1] = v.y;
        a[4 * i + 2] = v.z; a[4 * i + 3] = v.w;
    }
#pragma unroll
    for (int r = 0; r < R; ++r) a[r] *= ms[r];

    // FWHT-16 (Sylvester ordering); recursive /sqrt(n) => total 1/32
#pragma unroll
    for (int hstep = 1; hstep < R; hstep <<= 1) {
#pragma unroll
        for (int i = 0; i < R; ++i) {
            if ((i & hstep) == 0) {
                float u = a[i], v = a[i | hstep];
                a[i] = u + v; a[i | hstep] = u - v;
            }
        }
    }

    f4* dst = (f4*)(out + row * R);
#pragma unroll
    for (int i = 0; i < 4; ++i) {
        f4 v;
        v.x = a[4 * i + 0] * 0.03125f; v.y = a[4 * i + 1] * 0.03125f;
        v.z = a[4 * i + 2] * 0.03125f; v.w = a[4 * i + 3] * 0.03125f;
        __builtin_nontemporal_store(v, dst + i);
    }
}

extern "C" void kernel_launch(void* const* d_in, const int* in_sizes, int n_in,
                              void* d_out, int out_size, void* d_ws, size_t ws_size,
                              hipStream_t stream) {
    const float* hs    = (const float*)d_in[0];  // (8,4096,2048)
    const float* ra    = (const float*)d_in[1];  // (8,4096,16)
    const float* W1    = (const float*)d_in[2];  // (2048,32)
    const float* b1    = (const float*)d_in[3];  // (32)
    const float* gamma = (const float*)d_in[4];  // (32)
    const float* beta  = (const float*)d_in[5];  // (32)
    const float* W2    = (const float*)d_in[6];  // (32,16)
    const float* b2v   = (const float*)d_in[7];  // (16)
    const float* mlog  = (const float*)d_in[8];  // (16)
    const float* rsc   = (const float*)d_in[9];  // (16)
    float* out = (float*)d_out;

    float* xpart = (float*)d_ws;                 // 1024*32 f32 = 128 KB

    pool_proj    <<<dim3(SC, NB), 256, 0, stream>>>(hs, W1, xpart);
    ctrl_hadamard<<<256, 128, 0, stream>>>(xpart, b1, gamma, beta,
                                           W2, b2v, mlog, rsc, ra, out);
}